// Round 5
// baseline (441.251 us; speedup 1.0000x reference)
//
#include <hip/hip_runtime.h>
#include <hip/hip_bf16.h>
#include <stdint.h>

// Problem constants (B=4, S=2048, IN=4096, OUT=4096, FP=256)
// Harness dtype contract (verified R3): reference float16 tensors are
// delivered/read as FLOAT32; int8 -> int32; output read as float32.
#define N_TOK 8192
#define IN_F  4096
#define OUT_F 4096
#define FP_F  256
#define INT_F 3840

typedef int    v4i   __attribute__((ext_vector_type(4)));
typedef int    v16i  __attribute__((ext_vector_type(16)));
typedef float  v16f  __attribute__((ext_vector_type(16)));
typedef __bf16 bf16x8 __attribute__((ext_vector_type(8)));

// ---------------- workspace layout (bytes) ----------------
// UNPACKED biased int8 codes (R5): one byte per code, c = q+8 in [0,15].
// MFMA operand = raw 16B ds_read_b128 -> ZERO unpack VALU in the K-loop.
#define WS_QP   0u            // [N_TOK][INT_F] int8 codes, PRE-SWIZZLED
#define WS_WP   31457280u     // [OUT_F][INT_F] int8 codes, PRE-SWIZZLED
#define WS_FPX  47185920u     // [N_TOK][FP_F] bf16 outliers, PRE-SWIZZLED
#define WS_WFP  51380224u     // [OUT_F][FP_F] bf16 fp_weight, PRE-SWIZZLED
#define WS_F1   53477376u     // [N_TOK] float: scale
#define WS_F2   53510144u     // [N_TOK] float: -8*sumc*scale
#define WS_F3   53542912u     // [N_TOK] float: row min
#define WS_NEED 53575680u

// Biased-code algebra (verified passing): D = sum (q+8)(w+8);
// out = (D*sc + f2)*ws + f3*rw + bias + bf16_outlier_dot.
//
// SWIZZLE IS BAKED INTO THE WORKSPACE (gload_lds writes lane-linear, so the
// source carries the inverse permutation). All LDS rows are 64B = 4 slots
// of 16B; read addr = row*64 + (s ^ ((row>>1)&3))*16, so the bake is:
// logical 16B-group g stored at g' = (g&~3) | ((g&3) ^ ((row>>1)&3)).
// Row bits 1..2 only -> one baked layout serves every 256-aligned tile.
// (Same 4-slot geometry as the R1 bf16 phase, which ran conflict-free.)

__global__ __launch_bounds__(256) void zero_out_kernel(uint4* __restrict__ o) {
  o[(size_t)blockIdx.x * 256 + threadIdx.x] = uint4{0, 0, 0, 0};
}

// ---------------- fused prep kernel ----------------
// grid = [0,2048): quant, 4 tokens/block (1 wave/token, no __syncthreads)
//      | [2048,17408): pack_w | [17408,18432): conv_wfp
__global__ __launch_bounds__(256, 4) void prep_kernel(
    const float* __restrict__ x,
    const int* __restrict__ int_idx, const int* __restrict__ fp_idx,
    const int* __restrict__ int_w, const float* __restrict__ fp_w,
    uint8_t* __restrict__ qp, uint8_t* __restrict__ wp,
    __hip_bfloat16* __restrict__ fpx, __hip_bfloat16* __restrict__ wfp,
    float* __restrict__ f1, float* __restrict__ f2, float* __restrict__ f3) {
  int tid = threadIdx.x;
  int blk = blockIdx.x;

  if (blk >= 2048) {
    int pb = blk - 2048;
    if (pb < 15360) {
      // ---- pack_w: 4 int32 weights -> 4 biased byte codes, swizzled ----
      int t = pb * 256 + tid;                 // u32 index, 4096*960 total
      int r = t / 960, u = t % 960;
      const int* src = int_w + (size_t)r * INT_F + u * 4;
      int4 w4 = *(const int4*)src;
      uint32_t pk = (uint32_t)((w4.x + 8) & 15) |
                    (uint32_t)((w4.y + 8) & 15) << 8 |
                    (uint32_t)((w4.z + 8) & 15) << 16 |
                    (uint32_t)((w4.w + 8) & 15) << 24;
      int g = u >> 2;
      int gp = (g & ~3) | ((g & 3) ^ ((r >> 1) & 3));   // baked swizzle
      ((uint32_t*)wp)[(size_t)r * 960 + gp * 4 + (u & 3)] = pk;
    } else {
      // ---- conv_wfp: fp_weight f32 -> bf16, swizzled dest ----
      int t = (pb - 15360) * 256 + tid;
      int i = t * 4;
      int r = i >> 8, c = i & 255;
      float4 v = *(const float4*)(fp_w + i);
      __hip_bfloat16 b[4] = {__float2bfloat16(v.x), __float2bfloat16(v.y),
                             __float2bfloat16(v.z), __float2bfloat16(v.w)};
      int cs = (c & ~0x18) | (((((c) >> 3) & 3) ^ ((r >> 1) & 3)) << 3);  // baked bf16 swizzle
      *(uint2*)(wfp + (size_t)r * 256 + cs) = *(const uint2*)b;
    }
    return;
  }

  // ---- quant: one WAVE per token; lane l owns values i = 4l + 256k + j ----
  int wave = tid >> 6, l = tid & 63;
  int n = blk * 4 + wave;
  const float* xr = x + (size_t)n * IN_F;

  float v[60];
  float lmn = 1e30f, lmx = -1e30f;
#pragma unroll
  for (int k = 0; k < 15; k++) {
    int4 id = *(const int4*)&int_idx[4 * l + 256 * k];
    v[4 * k + 0] = xr[id.x]; v[4 * k + 1] = xr[id.y];
    v[4 * k + 2] = xr[id.z]; v[4 * k + 3] = xr[id.w];
#pragma unroll
    for (int j = 0; j < 4; j++) {
      lmn = fminf(lmn, v[4 * k + j]);
      lmx = fmaxf(lmx, v[4 * k + j]);
    }
  }
  // fp outlier gather (4 per lane); baked bf16 swizzle
  {
    int sw2 = (n >> 1) & 3;
#pragma unroll
    for (int j = 0; j < 4; j++) {
      int c = l + 64 * j;
      int cs = (c & ~0x18) | ((((c >> 3) & 3) ^ sw2) << 3);
      fpx[(size_t)n * FP_F + cs] = __float2bfloat16(xr[fp_idx[c]]);
    }
  }

  // wave-wide butterfly min/max -> every lane holds the result
#pragma unroll
  for (int off = 32; off > 0; off >>= 1) {
    lmn = fminf(lmn, __shfl_xor(lmn, off, 64));
    lmx = fmaxf(lmx, __shfl_xor(lmx, off, 64));
  }
  float mn = lmn;
  float sc = fmaxf((lmx - mn) / 15.0f, 1e-8f);   // IEEE f32 div, matches ref
  float inv = 1.0f / sc;
  if (l == 0) { f1[n] = sc; f3[n] = mn; }

  int sw4 = (n >> 1) & 3;                  // baked swizzle (uniform per wave)
  uint32_t* qrow = (uint32_t*)(qp + (size_t)n * INT_F);
  float lsum = 0.0f;
#pragma unroll
  for (int k = 0; k < 15; k++) {
    uint32_t pk = 0;
#pragma unroll
    for (int j = 0; j < 4; j++) {
      float c = fminf(fmaxf(rintf((v[4 * k + j] - mn) * inv), 0.0f), 15.0f);
      lsum += c;
      pk |= (uint32_t)c << (8 * j);
    }
    int g = (l >> 2) + 16 * k;
    int gp = (g & ~3) | ((g & 3) ^ sw4);
    qrow[gp * 4 + (l & 3)] = pk;           // coalesced within 64B windows
  }
#pragma unroll
  for (int off = 32; off > 0; off >>= 1) lsum += __shfl_xor(lsum, off, 64);
  if (l == 0) f2[n] = -8.0f * lsum * sc;   // exact: integer-valued f32 sums
}

__device__ __forceinline__ void gl16(const void* g, void* l) {
  __builtin_amdgcn_global_load_lds(
      (const __attribute__((address_space(1))) void*)g,
      (__attribute__((address_space(3))) void*)l, 16, 0, 0);
}

// Kernel 3 v8: 256x256 tile, 512 threads, 8 waves (2M x 4N), per-wave
// 128x64 = acc[4][2] of 32x32. m201-faithful phase schedule:
// per K-step (K=64 bytes) two phases of
//   { 6 ds_read_b128 | 2 global_load_lds -> barrier -> lgkmcnt(0)
//     -> sched_barrier -> setprio(1) 8 MFMA setprio(0) -> barrier }
// 3 LDS buffers x 32KB (96KB), staging 2 K-steps ahead; gates are
// s_waitcnt vmcnt(4) (NEVER 0 in steady state -- the R3 drain-0 bug was
// the confound, per m218 counted-vs-drain0 = +38-73%). bf16 phase uses
// the same structure (8 rounds of K=32, 3-buffer rotation).
// Unpacked int8 codes: operands load directly, zero unpack VALU.
__global__ __launch_bounds__(512, 2) void gemm_kernel(
    const uint8_t* __restrict__ qp, const uint8_t* __restrict__ wp,
    const __hip_bfloat16* __restrict__ fpx, const __hip_bfloat16* __restrict__ wfp,
    const float* __restrict__ f1, const float* __restrict__ f2,
    const float* __restrict__ f3,
    const float* __restrict__ wscale, const float* __restrict__ reduced,
    const float* __restrict__ bias, float* __restrict__ out) {
  __shared__ int4 lds4[6144];             // 96 KB = 3 buffers x (A 16K + B 16K)
  int8_t* lds = (int8_t*)lds4;

  int tid = threadIdx.x;
  int wave = tid >> 6, lane = tid & 63;
  int wm = wave >> 2, wn = wave & 3;      // 2 x 4 wave grid
  int blk = blockIdx.x;
  int wg = (blk & 7) * 64 + (blk >> 3);   // XCD swizzle (512 % 8 == 0, bijective)
  int tileM = wg & 31, tileN = wg >> 5;   // consecutive wg share tileN (B in L2)
  int n0 = tileM * 256, o0 = tileN * 256;

  union { v16i i; v16f f; } acc[4][2];
#pragma unroll
  for (int mi = 0; mi < 4; mi++)
#pragma unroll
    for (int ni = 0; ni < 2; ni++)
#pragma unroll
      for (int e = 0; e < 16; e++) acc[mi][ni].i[e] = 0;

  int m = lane & 31, kg = lane >> 5;

  // staging: 512 threads x 16B = 8KB = 128 rows x 64B per gl16.
  int row0 = tid >> 2, q16b = (tid & 3) * 16;
  int l0 = tid * 16;
  const uint8_t* gA0 = qp + (size_t)(n0 + row0) * INT_F + q16b;
  const uint8_t* gA1 = qp + (size_t)(n0 + 128 + row0) * INT_F + q16b;
  const uint8_t* gB0 = wp + (size_t)(o0 + row0) * INT_F + q16b;
  const uint8_t* gB1 = wp + (size_t)(o0 + 128 + row0) * INT_F + q16b;

#define STAGE_A(base, kt) do {                                   \
    gl16(gA0 + (kt) * 64, lds + (base) + l0);                    \
    gl16(gA1 + (kt) * 64, lds + (base) + 8192 + l0);             \
  } while (0)
#define STAGE_B(base, kt) do {                                   \
    gl16(gB0 + (kt) * 64, lds + (base) + 16384 + l0);            \
    gl16(gB1 + (kt) * 64, lds + (base) + 24576 + l0);            \
  } while (0)

  // ---------------- prologue: steps 0,1 into buf0,buf1 ----------------
  STAGE_A(0, 0); STAGE_B(0, 0);
  STAGE_A(32768, 1); STAGE_B(32768, 1);
  asm volatile("s_waitcnt vmcnt(4)" ::: "memory");   // step 0 landed
  __builtin_amdgcn_s_barrier();

  // ---------------- int4 phase: 60 K-steps of 64 codes ----------------
#pragma unroll 1
  for (int t = 0; t < 60; t++) {
    int rb = (t % 3) * 32768;
    int sb = ((t + 2) % 3) * 32768;
    bool st = (t + 2 < 60);
#pragma unroll
    for (int ks = 0; ks < 2; ks++) {
      int s = ks * 2 + kg;
      v4i a[4], b[2];
#pragma unroll
      for (int mi = 0; mi < 4; mi++) {
        int row = wm * 128 + mi * 32 + m;
        a[mi] = *(const v4i*)&lds[rb + row * 64 + ((s ^ ((row >> 1) & 3)) * 16)];
      }
#pragma unroll
      for (int ni = 0; ni < 2; ni++) {
        int row = wn * 64 + ni * 32 + m;
        b[ni] = *(const v4i*)&lds[rb + 16384 + row * 64 + ((s ^ ((row >> 1) & 3)) * 16)];
      }
      if (st) { if (ks == 0) STAGE_A(sb, t + 2); else STAGE_B(sb, t + 2); }
      __builtin_amdgcn_s_barrier();
      asm volatile("s_waitcnt lgkmcnt(0)" ::: "memory");
      __builtin_amdgcn_sched_barrier(0);
      __builtin_amdgcn_s_setprio(1);
#pragma unroll
      for (int mi = 0; mi < 4; mi++)
#pragma unroll
        for (int ni = 0; ni < 2; ni++)
          acc[mi][ni].i = __builtin_amdgcn_mfma_i32_32x32x32_i8(
              a[mi], b[ni], acc[mi][ni].i, 0, 0, 0);
      __builtin_amdgcn_s_setprio(0);
      if (ks == 1) {
        if (t < 58) asm volatile("s_waitcnt vmcnt(4)" ::: "memory");  // t+1 landed
        else        asm volatile("s_waitcnt vmcnt(0)" ::: "memory");  // epilogue
      }
      __builtin_amdgcn_s_barrier();
    }
  }

  // bf16 staging pointers (row stride 512B; kr selects 64B k-chunk)
  const uint8_t* fxb = (const uint8_t*)fpx;
  const uint8_t* fwb = (const uint8_t*)wfp;
  const uint8_t* gFA0 = fxb + (size_t)(n0 + row0) * 512 + q16b;
  const uint8_t* gFA1 = fxb + (size_t)(n0 + 128 + row0) * 512 + q16b;
  const uint8_t* gFB0 = fwb + (size_t)(o0 + row0) * 512 + q16b;
  const uint8_t* gFB1 = fwb + (size_t)(o0 + 128 + row0) * 512 + q16b;

#define STAGE_FA(base, kr) do {                                  \
    gl16(gFA0 + (kr) * 64, lds + (base) + l0);                   \
    gl16(gFA1 + (kr) * 64, lds + (base) + 8192 + l0);            \
  } while (0)
#define STAGE_FB(base, kr) do {                                  \
    gl16(gFB0 + (kr) * 64, lds + (base) + 16384 + l0);           \
    gl16(gFB1 + (kr) * 64, lds + (base) + 24576 + l0);           \
  } while (0)

  // stage bf16 round 0 into buf0 now (int read buf2 last; buf0/1 free);
  // its latency hides under the dequant fold's VALU + its scalar loads.
  STAGE_FA(0, 0); STAGE_FB(0, 0);

  // -------- in-place dequant fold: acc.i -> acc.f (exact, D < 2^24) --------
  int col = lane & 31, rb4 = (lane >> 5) * 4;
  float cws[2], crw[2], cbs[2];
#pragma unroll
  for (int ni = 0; ni < 2; ni++) {
    int o = o0 + wn * 64 + ni * 32 + col;
    cws[ni] = wscale[o]; crw[ni] = reduced[o]; cbs[ni] = bias[o];
  }
#pragma unroll
  for (int mi = 0; mi < 4; mi++) {
#pragma unroll
    for (int reg = 0; reg < 16; reg++) {
      int row = (reg & 3) + 8 * (reg >> 2) + rb4;
      int n = n0 + wm * 128 + mi * 32 + row;
      float a1 = f1[n], a2 = f2[n], a3 = f3[n];
      float d0 = (float)acc[mi][0].i[reg];
      float d1 = (float)acc[mi][1].i[reg];
      acc[mi][0].f[reg] = (d0 * a1 + a2) * cws[0] + a3 * crw[0] + cbs[0];
      acc[mi][1].f[reg] = (d1 * a1 + a2) * cws[1] + a3 * crw[1] + cbs[1];
    }
  }
  // fold's own scalar-load waits drained round 0's gl16 (issued earlier,
  // in-order vmcnt). Stage round 1, publish round 0.
  STAGE_FA(32768, 1); STAGE_FB(32768, 1);
  __builtin_amdgcn_s_barrier();

  // ---------------- bf16 phase: 8 rounds of K=32, 3-buf rotation ----------
#pragma unroll 1
  for (int r = 0; r < 8; r++) {
    int rb = (r % 3) * 32768;
    int sb = ((r + 2) % 3) * 32768;
    bool st = (r + 2 < 8);
#pragma unroll
    for (int u = 0; u < 2; u++) {
      int s = u * 2 + kg;
      bf16x8 a[4], b[2];
#pragma unroll
      for (int mi = 0; mi < 4; mi++) {
        int row = wm * 128 + mi * 32 + m;
        a[mi] = *(const bf16x8*)&lds[rb + row * 64 + ((s ^ ((row >> 1) & 3)) * 16)];
      }
#pragma unroll
      for (int ni = 0; ni < 2; ni++) {
        int row = wn * 64 + ni * 32 + m;
        b[ni] = *(const bf16x8*)&lds[rb + 16384 + row * 64 + ((s ^ ((row >> 1) & 3)) * 16)];
      }
      if (st) { if (u == 0) STAGE_FA(sb, r + 2); else STAGE_FB(sb, r + 2); }
      __builtin_amdgcn_s_barrier();
      asm volatile("s_waitcnt lgkmcnt(0)" ::: "memory");
      __builtin_amdgcn_sched_barrier(0);
      __builtin_amdgcn_s_setprio(1);
#pragma unroll
      for (int mi = 0; mi < 4; mi++)
#pragma unroll
        for (int ni = 0; ni < 2; ni++)
          acc[mi][ni].f = __builtin_amdgcn_mfma_f32_32x32x16_bf16(
              a[mi], b[ni], acc[mi][ni].f, 0, 0, 0);
      __builtin_amdgcn_s_setprio(0);
      if (u == 1) {
        if (r < 6) asm volatile("s_waitcnt vmcnt(4)" ::: "memory");   // r+1 landed
        else       asm volatile("s_waitcnt vmcnt(0)" ::: "memory");   // epilogue
      }
      __builtin_amdgcn_s_barrier();
    }
  }
#undef STAGE_A
#undef STAGE_B
#undef STAGE_FA
#undef STAGE_FB

  // ---------------- store (f32) ----------------
#pragma unroll
  for (int mi = 0; mi < 4; mi++) {
#pragma unroll
    for (int ni = 0; ni < 2; ni++) {
      int o = o0 + wn * 64 + ni * 32 + col;
#pragma unroll
      for (int reg = 0; reg < 16; reg++) {
        int row = (reg & 3) + 8 * (reg >> 2) + rb4;
        int n = n0 + wm * 128 + mi * 32 + row;
        out[(size_t)n * OUT_F + o] = acc[mi][ni].f[reg];
      }
    }
  }
}

extern "C" void kernel_launch(void* const* d_in, const int* in_sizes, int n_in,
                              void* d_out, int out_size, void* d_ws, size_t ws_size,
                              hipStream_t stream) {
  const float* x     = (const float*)d_in[0];
  const int*   int_w = (const int*)d_in[1];
  const float* fp_w  = (const float*)d_in[2];
  const float* bias  = (const float*)d_in[3];
  const float* wsc   = (const float*)d_in[4];
  const float* red   = (const float*)d_in[5];
  const int*   iidx  = (const int*)d_in[6];
  const int*   fidx  = (const int*)d_in[7];
  float*       out   = (float*)d_out;

  if (ws_size < (size_t)WS_NEED) {
    zero_out_kernel<<<out_size / 1024, 256, 0, stream>>>((uint4*)d_out);
    return;
  }

  uint8_t* ws = (uint8_t*)d_ws;
  uint8_t*        qp  = ws + WS_QP;
  uint8_t*        wpk = ws + WS_WP;
  __hip_bfloat16* fpx = (__hip_bfloat16*)(ws + WS_FPX);
  __hip_bfloat16* wfp = (__hip_bfloat16*)(ws + WS_WFP);
  float*          f1  = (float*)(ws + WS_F1);
  float*          f2  = (float*)(ws + WS_F2);
  float*          f3  = (float*)(ws + WS_F3);

  // fused prep: quant (2048 blocks, 1 wave/token) | pack_w (15360) | conv (1024)
  prep_kernel<<<2048 + 15360 + 1024, 256, 0, stream>>>(
      x, iidx, fidx, int_w, fp_w, qp, wpk, fpx, wfp, f1, f2, f3);
  // 256x256 tiles: 32 x 16 = 512 blocks of 512 threads (1 block/CU, 2 rounds)
  gemm_kernel<<<(N_TOK / 256) * (OUT_F / 256), 512, 0, stream>>>(
      qp, wpk, fpx, wfp, f1, f2, f3, wsc, red, bias, out);
}